// Round 2
// baseline (424.643 us; speedup 1.0000x reference)
//
#include <hip/hip_runtime.h>
#include <hip/hip_bf16.h>
#include <math.h>

typedef unsigned int u32;
typedef unsigned short u16;
typedef __bf16 bf16x8 __attribute__((ext_vector_type(8)));
typedef float f32x4 __attribute__((ext_vector_type(4)));
typedef u32 u32x4 __attribute__((ext_vector_type(4)));
typedef u32 u32x2 __attribute__((ext_vector_type(2)));

#define T_DATA 500000
#define KNO    200          // T_no (kernel length)
#define SUB    20
#define E_NO   200
#define I_NO   50
#define NBAS   13
#define PI_F   3.14159265358979f
#define KKN    7            // conv K-tiles: 7*32 = 224 window
#define P_SZ   (T_DATA*SUB) // 10,000,000
#define MT_TOT (T_DATA/16)  // 31250

__device__ __forceinline__ float bf2f(u16 v){
  union { u32 u; float f; } x; x.u = ((u32)v) << 16; return x.f;
}
__device__ __forceinline__ u16 f2bf(float f){
  union { float f; u32 u; } x; x.f = f;
  u32 u = x.u;
  return (u16)((u + 0x7FFFu + ((u >> 16) & 1u)) >> 16);
}
__device__ __forceinline__ u16 trunc_bf(float f){   // exact for 0.0/1.0 spikes
  union { float f; u32 u; } x; x.f = f;
  return (u16)(x.u >> 16);
}

// kernel-bank value k_{type,s}[j];  type: 0=e,1=i,2=spk,3=hist   (all params f32)
__device__ __forceinline__ float filt_val(int type, int s, int j,
    const float* Tau, const float* Del, const float* Wsyn,
    const float* Wspk, const float* Whist){
  if (type < 2){
    float tau = Tau[s*2+type];
    float del = Del[s*2+type];
    float w   = Wsyn[s*2+type];
    float t   = fmaxf((float)j - del, 0.0f);
    float tt  = t / (tau*tau);
    float v   = tt * expf(-tt) * (w*w);
    return (type == 1) ? -v : v;
  } else {
    const float* W = (type == 2) ? Wspk : Whist;
    float raw = 3.0f * logf((float)j + 1.0f);
    float acc = 0.0f;
#pragma unroll
    for (int b = 0; b < NBAS; b++){
      float d = raw - 0.5f*PI_F*(float)b;
      float bas = (d >= -PI_F && d <= PI_F) ? (0.5f*cosf(d) + 0.5f) : 0.0f;
      acc += W[s*NBAS + b] * bas;
    }
    return acc;
  }
}

// ---- K0a: write out_filters (vstack e,i,spk,hist) to tail of d_out (f32) ----
__global__ void k_filters(const float* Tau, const float* Del, const float* Wsyn,
                          const float* Wspk, const float* Whist, float* out){
  int r = blockIdx.x;              // 0..79
  int type = r / SUB, s = r % SUB;
  for (int j = threadIdx.x; j < KNO; j += blockDim.x)
    out[P_SZ + r*KNO + j] = filt_val(type, s, j, Tau, Del, Wsyn, Wspk, Whist);
}

// ---- K0b: conv A-fragments (kernel Toeplitz), ready-to-load per-lane 16B ----
// A_kk[m][u'] = k[off+m-1-u'], off = 200-32*kk ; layout [(type*SUB+s)*KKN+kk][lane*8]
__global__ void k_afrag(const float* Tau, const float* Del, const float* Wsyn,
                        const float* Wspk, const float* Whist, u16* afrag){
  int b = blockIdx.x;              // ((type*SUB)+s)*KKN + kk
  int kk = b % KKN;
  int ts = b / KKN;
  int type = ts / SUB, s = ts % SUB;
  __shared__ float kf[KNO];
  for (int j = threadIdx.x; j < KNO; j += 64)
    kf[j] = filt_val(type, s, j, Tau, Del, Wsyn, Wspk, Whist);
  __syncthreads();
  int l = threadIdx.x;
  int m = l & 15, kg = l >> 4;
  int off = 200 - 32*kk;
  u32 p[4];
#pragma unroll
  for (int h = 0; h < 4; h++){
    int u0 = kg*8 + 2*h;
    int i0 = off + m - 1 - u0;
    int i1 = i0 - 1;
    u16 lo = (i0 >= 0 && i0 < KNO) ? f2bf(kf[i0]) : (u16)0;
    u16 hi = (i1 >= 0 && i1 < KNO) ? f2bf(kf[i1]) : (u16)0;
    p[h] = (u32)lo | ((u32)hi << 16);
  }
  u32* dst = (u32*)(afrag + (size_t)b*512 + l*8);
  dst[0]=p[0]; dst[1]=p[1]; dst[2]=p[2]; dst[3]=p[3];
}

// ---- K0c: gather B-fragments (C_e^T, C_i^T, identity for Z), f32 -> bf16 ----
// layout: e at 0 (2 ntiles * 7 kt * 512), i at 7168 (2*2*512), z at 9216 (2*1*512)
__global__ void k_bfrag(const float* Ce, const float* Ci, u16* bfrag){
  const int NE = 2*7*512, NI = 2*2*512, NZ = 2*1*512;
  for (int x = threadIdx.x + blockIdx.x*blockDim.x; x < NE+NI+NZ; x += blockDim.x*gridDim.x){
    int src, base, KT;
    if (x < NE){ src=0; base=x;       KT=7; }
    else if (x < NE+NI){ src=1; base=x-NE;    KT=2; }
    else {               src=2; base=x-NE-NI; KT=1; }
    int nt = base / (KT*512);
    int rem = base % (KT*512);
    int kt = rem / 512;
    int le = rem % 512;
    int l = le / 8, e = le % 8;
    int n = nt*16 + (l & 15);
    int k = kt*32 + (l >> 4)*8 + e;
    u16 v = 0;
    if (src == 0){ if (n < SUB && k < E_NO) v = trunc_bf(Ce[n*E_NO + k]); }
    else if (src == 1){ if (n < SUB && k < I_NO) v = trunc_bf(Ci[n*I_NO + k]); }
    else { if (n < SUB && k == n) v = trunc_bf(1.0f); }
    bfrag[x] = v;
  }
}

// ---- K1: gather via MFMA: dst[s][t] = sum_k src[t][k] * Bfrag[k][s] ----
// src is f32 (0/1 spikes), converted to bf16 by truncation (exact).
template<int W, int KT>
__global__ __launch_bounds__(256) void k_gather(const float* __restrict__ src,
                                                const u16* __restrict__ bfrag,
                                                u16* __restrict__ dst){
  int wv = threadIdx.x >> 6, lane = threadIdx.x & 63;
  int mt = blockIdx.x*4 + wv;
  if (mt >= MT_TOT) return;
  int t0 = mt*16;
  int m = lane & 15, kg = lane >> 4;
  f32x4 acc0 = {0.f,0.f,0.f,0.f}, acc1 = {0.f,0.f,0.f,0.f};
  const size_t NW = (size_t)T_DATA * W;
#pragma unroll
  for (int kt = 0; kt < KT; kt++){
    size_t cs = (size_t)(t0 + m)*W + kt*32 + kg*8;
    union { bf16x8 v; u16 h[8]; } au;
    if (cs + 8 <= NW){
      u32 wbits[8];
      if (W == 50){                        // rows only 8B-aligned
        u32x2 a = *(const u32x2*)(src + cs);
        u32x2 b = *(const u32x2*)(src + cs + 2);
        u32x2 c = *(const u32x2*)(src + cs + 4);
        u32x2 d = *(const u32x2*)(src + cs + 6);
        wbits[0]=a[0]; wbits[1]=a[1]; wbits[2]=b[0]; wbits[3]=b[1];
        wbits[4]=c[0]; wbits[5]=c[1]; wbits[6]=d[0]; wbits[7]=d[1];
      } else {                             // 16B-aligned
        u32x4 a = *(const u32x4*)(src + cs);
        u32x4 b = *(const u32x4*)(src + cs + 4);
        wbits[0]=a[0]; wbits[1]=a[1]; wbits[2]=a[2]; wbits[3]=a[3];
        wbits[4]=b[0]; wbits[5]=b[1]; wbits[6]=b[2]; wbits[7]=b[3];
      }
#pragma unroll
      for (int e = 0; e < 8; e++) au.h[e] = (u16)(wbits[e] >> 16);
    } else {
#pragma unroll
      for (int e = 0; e < 8; e++){
        size_t idx = cs + e;
        au.h[e] = (idx < NW) ? trunc_bf(src[idx]) : (u16)0;
      }
    }
    bf16x8 b0 = *(const bf16x8*)(bfrag + kt*512 + lane*8);
    bf16x8 b1 = *(const bf16x8*)(bfrag + (KT + kt)*512 + lane*8);
    acc0 = __builtin_amdgcn_mfma_f32_16x16x32_bf16(au.v, b0, acc0, 0, 0, 0);
    acc1 = __builtin_amdgcn_mfma_f32_16x16x32_bf16(au.v, b1, acc1, 0, 0, 0);
  }
  int i0 = kg*4;   // C/D: col = lane&15 (channel), row = 4*kg + reg (t-offset)
  {
    u32 lo = (u32)f2bf(acc0[0]) | ((u32)f2bf(acc0[1]) << 16);
    u32 hi = (u32)f2bf(acc0[2]) | ((u32)f2bf(acc0[3]) << 16);
    u32* d = (u32*)(dst + (size_t)m*T_DATA + t0 + i0);
    d[0] = lo; d[1] = hi;
  }
  if (m < SUB - 16){
    u32 lo = (u32)f2bf(acc1[0]) | ((u32)f2bf(acc1[1]) << 16);
    u32 hi = (u32)f2bf(acc1[2]) | ((u32)f2bf(acc1[3]) << 16);
    u32* d = (u32*)(dst + (size_t)(16 + m)*T_DATA + t0 + i0);
    d[0] = lo; d[1] = hi;
  }
}

// ---- K2: 4 grouped FIR convs via MFMA + fused mix/sigmoid epilogue ----
#define TCH 256
#define WIN 464
#define WSTR 488
#define NCHK 4
#define NCHUNKS_TOT ((T_DATA + TCH - 1)/TCH)   // 1954

__global__ __launch_bounds__(512) void k_conv(
    const u16* __restrict__ xe, const u16* __restrict__ xi,
    const u16* __restrict__ zt, const u16* __restrict__ afrag,
    const float* __restrict__ Cden, const float* __restrict__ Theta,
    float* __restrict__ out)
{
  __shared__ __align__(16) u16 ls[3*SUB*WSTR];   // 58,560 B (stage, reused for results)
  __shared__ float lcden[SUB*SUB];
  __shared__ float lth[SUB];

  int tid = threadIdx.x;
  if (tid < SUB*SUB) lcden[tid] = Cden[tid];
  else if (tid < SUB*SUB + SUB) lth[tid - SUB*SUB] = Theta[tid - SUB*SUB];

  int wv = tid >> 6, lane = tid & 63;
  int m = lane & 15, kg = lane >> 4;
  int bofflane = 16*m + 8*kg;   // B-frag LDS element offset (per lane)
  int toff = 16*m + 4*kg;       // C-tile t-offset for this lane

  for (int ic = 0; ic < NCHK; ic++){
    int c = blockIdx.x*NCHK + ic;
    if (c >= NCHUNKS_TOT) break;
    int t0c = c * TCH;

    __syncthreads();   // protects LDS reuse across iterations (and lcden on iter 0)

    // ---- stage windows x[t0c-200 .. t0c+264) for all 3 arrays x 20 channels ----
    for (int w = tid; w < 3*SUB*(WIN/8); w += 512){
      int arr = w / (SUB*(WIN/8));
      int rem = w - arr*(SUB*(WIN/8));
      int s   = rem / (WIN/8);
      int i8  = rem - s*(WIN/8);
      int g0  = t0c - 200 + i8*8;
      const u16* gp = (arr == 0 ? xe : (arr == 1 ? xi : zt)) + (size_t)s*T_DATA;
      u16* lp = ls + (arr*SUB + s)*WSTR + i8*8;
      if (g0 >= 0 && g0 + 8 <= T_DATA){
        *(bf16x8*)lp = *(const bf16x8*)(gp + g0);
      } else {
#pragma unroll
        for (int e = 0; e < 8; e++){
          int g = g0 + e;
          lp[e] = (g >= 0 && g < T_DATA) ? gp[g] : (u16)0;
        }
      }
    }
    __syncthreads();

    // ---- MFMA: waves 0-3 do syn(e+i) for 5 channels each; waves 4-7 do spk+hist ----
    f32x4 accA[5], accB[5];
    if (wv < 4){
#pragma unroll
      for (int q = 0; q < 5; q++){
        int ch = wv*5 + q;
        f32x4 acc = {0.f,0.f,0.f,0.f};
        const u16* be = ls + (0*SUB + ch)*WSTR;
        const u16* bi = ls + (1*SUB + ch)*WSTR;
        const u16* ae = afrag + (size_t)((0*SUB + ch)*KKN)*512 + lane*8;
        const u16* ai = afrag + (size_t)((1*SUB + ch)*KKN)*512 + lane*8;
#pragma unroll
        for (int kk = 0; kk < KKN; kk++){
          int bo = 32*kk + bofflane;
          acc = __builtin_amdgcn_mfma_f32_16x16x32_bf16(
                  *(const bf16x8*)(ae + kk*512), *(const bf16x8*)(be + bo), acc, 0,0,0);
          acc = __builtin_amdgcn_mfma_f32_16x16x32_bf16(
                  *(const bf16x8*)(ai + kk*512), *(const bf16x8*)(bi + bo), acc, 0,0,0);
        }
        accA[q] = acc;
      }
    } else {
#pragma unroll
      for (int q = 0; q < 5; q++){
        int ch = (wv - 4)*5 + q;
        f32x4 as = {0.f,0.f,0.f,0.f}, ah = {0.f,0.f,0.f,0.f};
        const u16* bz = ls + (2*SUB + ch)*WSTR;
        const u16* a2 = afrag + (size_t)((2*SUB + ch)*KKN)*512 + lane*8;
        const u16* a3 = afrag + (size_t)((3*SUB + ch)*KKN)*512 + lane*8;
#pragma unroll
        for (int kk = 0; kk < KKN; kk++){
          int bo = 32*kk + bofflane;
          bf16x8 b = *(const bf16x8*)(bz + bo);
          as = __builtin_amdgcn_mfma_f32_16x16x32_bf16(*(const bf16x8*)(a2 + kk*512), b, as, 0,0,0);
          ah = __builtin_amdgcn_mfma_f32_16x16x32_bf16(*(const bf16x8*)(a3 + kk*512), b, ah, 0,0,0);
        }
        accA[q] = as; accB[q] = ah;
      }
    }
    __syncthreads();   // all stage reads complete

    // ---- write conv results into reused LDS: rows [syn0..19][spk0..19][hist0..19] ----
    u16* rr = ls;
    if (wv < 4){
#pragma unroll
      for (int q = 0; q < 5; q++){
        int ch = wv*5 + q;
        u32* d = (u32*)(rr + (0*SUB + ch)*TCH + toff);
        d[0] = (u32)f2bf(accA[q][0]) | ((u32)f2bf(accA[q][1]) << 16);
        d[1] = (u32)f2bf(accA[q][2]) | ((u32)f2bf(accA[q][3]) << 16);
      }
    } else {
#pragma unroll
      for (int q = 0; q < 5; q++){
        int ch = (wv - 4)*5 + q;
        u32* d1 = (u32*)(rr + (1*SUB + ch)*TCH + toff);
        d1[0] = (u32)f2bf(accA[q][0]) | ((u32)f2bf(accA[q][1]) << 16);
        d1[1] = (u32)f2bf(accA[q][2]) | ((u32)f2bf(accA[q][3]) << 16);
        u32* d2 = (u32*)(rr + (2*SUB + ch)*TCH + toff);
        d2[0] = (u32)f2bf(accB[q][0]) | ((u32)f2bf(accB[q][1]) << 16);
        d2[1] = (u32)f2bf(accB[q][2]) | ((u32)f2bf(accB[q][3]) << 16);
      }
    }
    __syncthreads();

    // ---- epilogue: P = sigmoid(syn + theta + hist + Cden @ spk), direct f32 out ----
    int t = tid >> 1, h = tid & 1;
    float spkv[SUB];
#pragma unroll
    for (int s = 0; s < SUB; s++) spkv[s] = bf2f(rr[(SUB + s)*TCH + t]);
    float res[10];
#pragma unroll
    for (int j = 0; j < 10; j++){
      int sp = h*10 + j;
      float msum = bf2f(rr[sp*TCH + t]) + lth[sp] + bf2f(rr[(2*SUB + sp)*TCH + t]);
#pragma unroll
      for (int s = 0; s < SUB; s++) msum += lcden[sp*SUB + s] * spkv[s];
      res[j] = 1.0f/(1.0f + expf(-msum));
    }
    if (t0c + t < T_DATA){
      float2* d = (float2*)(out + (size_t)(t0c + t)*SUB + h*10);
#pragma unroll
      for (int j = 0; j < 5; j++){
        float2 v; v.x = res[2*j]; v.y = res[2*j+1];
        d[j] = v;
      }
    }
  }
}

extern "C" void kernel_launch(void* const* d_in, const int* in_sizes, int n_in,
                              void* d_out, int out_size, void* d_ws, size_t ws_size,
                              hipStream_t stream){
  const float* S_e  = (const float*)d_in[0];
  const float* S_i  = (const float*)d_in[1];
  const float* Z    = (const float*)d_in[2];
  const float* Cden = (const float*)d_in[3];
  const float* C_e  = (const float*)d_in[4];
  const float* C_i  = (const float*)d_in[5];
  const float* Tau  = (const float*)d_in[6];
  const float* Del  = (const float*)d_in[7];
  const float* Wsyn = (const float*)d_in[8];
  const float* Wspk = (const float*)d_in[9];
  const float* Whist= (const float*)d_in[10];
  const float* Theta= (const float*)d_in[11];
  float* out = (float*)d_out;

  // workspace layout (bf16 elements)
  u16* xe    = (u16*)d_ws;
  u16* xi    = xe + (size_t)SUB*T_DATA;
  u16* zt    = xi + (size_t)SUB*T_DATA;
  u16* afrag = zt + (size_t)SUB*T_DATA;            // 4*20*7*512
  u16* bfrag = afrag + (size_t)4*SUB*KKN*512;      // 10240
  size_t need = ((size_t)3*SUB*T_DATA + (size_t)4*SUB*KKN*512 + 10240) * 2;
  if (ws_size < need) return;   // ~60.6 MB required

  k_filters<<<4*SUB, 64, 0, stream>>>(Tau, Del, Wsyn, Wspk, Whist, out);
  k_afrag<<<4*SUB*KKN, 64, 0, stream>>>(Tau, Del, Wsyn, Wspk, Whist, afrag);
  k_bfrag<<<4, 256, 0, stream>>>(C_e, C_i, bfrag);

  int gblk = (MT_TOT + 3)/4;
  k_gather<200,7><<<gblk, 256, 0, stream>>>(S_e, bfrag, xe);
  k_gather<50, 2><<<gblk, 256, 0, stream>>>(S_i, bfrag + 2*7*512, xi);
  k_gather<20, 1><<<gblk, 256, 0, stream>>>(Z,  bfrag + 2*7*512 + 2*2*512, zt);

  k_conv<<<(NCHUNKS_TOT + NCHK - 1)/NCHK, 512, 0, stream>>>(
      xe, xi, zt, afrag, Cden, Theta, out);
}

// Round 3
// 321.378 us; speedup vs baseline: 1.3213x; 1.3213x over previous
//
#include <hip/hip_runtime.h>
#include <hip/hip_bf16.h>
#include <math.h>

typedef unsigned int u32;
typedef unsigned short u16;
typedef __bf16 bf16x8 __attribute__((ext_vector_type(8)));
typedef float f32x4 __attribute__((ext_vector_type(4)));
typedef u32 u32x4 __attribute__((ext_vector_type(4)));
typedef u32 u32x2 __attribute__((ext_vector_type(2)));

#define T_DATA 500000
#define KNO    200          // T_no (kernel length)
#define SUB    20
#define E_NO   200
#define I_NO   50
#define NBAS   13
#define PI_F   3.14159265358979f
#define KKN    7            // conv K-tiles: 7*32 = 224 window
#define P_SZ   (T_DATA*SUB) // 10,000,000
#define MT_TOT (T_DATA/16)  // 31250
#define TCH    256
#define NCHUNKS_TOT ((T_DATA + TCH - 1)/TCH)   // 1954

__device__ __forceinline__ float bf2f(u16 v){
  union { u32 u; float f; } x; x.u = ((u32)v) << 16; return x.f;
}
__device__ __forceinline__ u16 f2bf(float f){
  union { float f; u32 u; } x; x.f = f;
  u32 u = x.u;
  return (u16)((u + 0x7FFFu + ((u >> 16) & 1u)) >> 16);
}
__device__ __forceinline__ u16 trunc_bf(float f){   // exact for 0.0/1.0 spikes
  union { float f; u32 u; } x; x.f = f;
  return (u16)(x.u >> 16);
}

// kernel-bank value k_{type,s}[j];  type: 0=e,1=i,2=spk,3=hist   (all params f32)
__device__ __forceinline__ float filt_val(int type, int s, int j,
    const float* Tau, const float* Del, const float* Wsyn,
    const float* Wspk, const float* Whist){
  if (type < 2){
    float tau = Tau[s*2+type];
    float del = Del[s*2+type];
    float w   = Wsyn[s*2+type];
    float t   = fmaxf((float)j - del, 0.0f);
    float tt  = t / (tau*tau);
    float v   = tt * expf(-tt) * (w*w);
    return (type == 1) ? -v : v;
  } else {
    const float* W = (type == 2) ? Wspk : Whist;
    float raw = 3.0f * logf((float)j + 1.0f);
    float acc = 0.0f;
#pragma unroll
    for (int b = 0; b < NBAS; b++){
      float d = raw - 0.5f*PI_F*(float)b;
      float bas = (d >= -PI_F && d <= PI_F) ? (0.5f*cosf(d) + 0.5f) : 0.0f;
      acc += W[s*NBAS + b] * bas;
    }
    return acc;
  }
}

// ---- K0a: write out_filters (vstack e,i,spk,hist) to tail of d_out (f32) ----
__global__ void k_filters(const float* Tau, const float* Del, const float* Wsyn,
                          const float* Wspk, const float* Whist, float* out){
  int r = blockIdx.x;              // 0..79
  int type = r / SUB, s = r % SUB;
  for (int j = threadIdx.x; j < KNO; j += blockDim.x)
    out[P_SZ + r*KNO + j] = filt_val(type, s, j, Tau, Del, Wsyn, Wspk, Whist);
}

// ---- K0b: conv A-fragments (kernel Toeplitz), ready-to-load per-lane 16B ----
// A_kk[m][u'] = k[off+m-1-u'], off = 200-32*kk ; layout [(type*SUB+s)*KKN+kk][lane*8]
__global__ void k_afrag(const float* Tau, const float* Del, const float* Wsyn,
                        const float* Wspk, const float* Whist, u16* afrag){
  int b = blockIdx.x;              // ((type*SUB)+s)*KKN + kk
  int kk = b % KKN;
  int ts = b / KKN;
  int type = ts / SUB, s = ts % SUB;
  __shared__ float kf[KNO];
  for (int j = threadIdx.x; j < KNO; j += 64)
    kf[j] = filt_val(type, s, j, Tau, Del, Wsyn, Wspk, Whist);
  __syncthreads();
  int l = threadIdx.x;
  int m = l & 15, kg = l >> 4;
  int off = 200 - 32*kk;
  u32 p[4];
#pragma unroll
  for (int h = 0; h < 4; h++){
    int u0 = kg*8 + 2*h;
    int i0 = off + m - 1 - u0;
    int i1 = i0 - 1;
    u16 lo = (i0 >= 0 && i0 < KNO) ? f2bf(kf[i0]) : (u16)0;
    u16 hi = (i1 >= 0 && i1 < KNO) ? f2bf(kf[i1]) : (u16)0;
    p[h] = (u32)lo | ((u32)hi << 16);
  }
  u32* dst = (u32*)(afrag + (size_t)b*512 + l*8);
  dst[0]=p[0]; dst[1]=p[1]; dst[2]=p[2]; dst[3]=p[3];
}

// ---- K0c: gather B-fragments (C_e^T, C_i^T, identity for Z), f32 -> bf16 ----
__global__ void k_bfrag(const float* Ce, const float* Ci, u16* bfrag){
  const int NE = 2*7*512, NI = 2*2*512, NZ = 2*1*512;
  for (int x = threadIdx.x + blockIdx.x*blockDim.x; x < NE+NI+NZ; x += blockDim.x*gridDim.x){
    int src, base, KT;
    if (x < NE){ src=0; base=x;       KT=7; }
    else if (x < NE+NI){ src=1; base=x-NE;    KT=2; }
    else {               src=2; base=x-NE-NI; KT=1; }
    int nt = base / (KT*512);
    int rem = base % (KT*512);
    int kt = rem / 512;
    int le = rem % 512;
    int l = le / 8, e = le % 8;
    int n = nt*16 + (l & 15);
    int k = kt*32 + (l >> 4)*8 + e;
    u16 v = 0;
    if (src == 0){ if (n < SUB && k < E_NO) v = trunc_bf(Ce[n*E_NO + k]); }
    else if (src == 1){ if (n < SUB && k < I_NO) v = trunc_bf(Ci[n*I_NO + k]); }
    else { if (n < SUB && k == n) v = trunc_bf(1.0f); }
    bfrag[x] = v;
  }
}

// ---- K1: gather via MFMA: dst[s][t] = sum_k src[t][k] * Bfrag[k][s] ----
template<int W, int KT>
__global__ __launch_bounds__(256) void k_gather(const float* __restrict__ src,
                                                const u16* __restrict__ bfrag,
                                                u16* __restrict__ dst){
  int wv = threadIdx.x >> 6, lane = threadIdx.x & 63;
  int mt = blockIdx.x*4 + wv;
  if (mt >= MT_TOT) return;
  int t0 = mt*16;
  int m = lane & 15, kg = lane >> 4;
  f32x4 acc0 = {0.f,0.f,0.f,0.f}, acc1 = {0.f,0.f,0.f,0.f};
  const size_t NW = (size_t)T_DATA * W;
#pragma unroll
  for (int kt = 0; kt < KT; kt++){
    size_t cs = (size_t)(t0 + m)*W + kt*32 + kg*8;
    union { bf16x8 v; u16 h[8]; } au;
    if (cs + 8 <= NW){
      u32 wbits[8];
      if (W == 50){                        // rows only 8B-aligned
        u32x2 a = *(const u32x2*)(src + cs);
        u32x2 b = *(const u32x2*)(src + cs + 2);
        u32x2 c = *(const u32x2*)(src + cs + 4);
        u32x2 d = *(const u32x2*)(src + cs + 6);
        wbits[0]=a[0]; wbits[1]=a[1]; wbits[2]=b[0]; wbits[3]=b[1];
        wbits[4]=c[0]; wbits[5]=c[1]; wbits[6]=d[0]; wbits[7]=d[1];
      } else {                             // 16B-aligned
        u32x4 a = *(const u32x4*)(src + cs);
        u32x4 b = *(const u32x4*)(src + cs + 4);
        wbits[0]=a[0]; wbits[1]=a[1]; wbits[2]=a[2]; wbits[3]=a[3];
        wbits[4]=b[0]; wbits[5]=b[1]; wbits[6]=b[2]; wbits[7]=b[3];
      }
#pragma unroll
      for (int e = 0; e < 8; e++) au.h[e] = (u16)(wbits[e] >> 16);
    } else {
#pragma unroll
      for (int e = 0; e < 8; e++){
        size_t idx = cs + e;
        au.h[e] = (idx < NW) ? trunc_bf(src[idx]) : (u16)0;
      }
    }
    bf16x8 b0 = *(const bf16x8*)(bfrag + kt*512 + lane*8);
    bf16x8 b1 = *(const bf16x8*)(bfrag + (KT + kt)*512 + lane*8);
    acc0 = __builtin_amdgcn_mfma_f32_16x16x32_bf16(au.v, b0, acc0, 0, 0, 0);
    acc1 = __builtin_amdgcn_mfma_f32_16x16x32_bf16(au.v, b1, acc1, 0, 0, 0);
  }
  int i0 = kg*4;   // C/D: t = 16*(lane&15) + 4*kg + reg ; channel = row block
  {
    u32 lo = (u32)f2bf(acc0[0]) | ((u32)f2bf(acc0[1]) << 16);
    u32 hi = (u32)f2bf(acc0[2]) | ((u32)f2bf(acc0[3]) << 16);
    u32* d = (u32*)(dst + (size_t)m*T_DATA + t0 + i0);
    d[0] = lo; d[1] = hi;
  }
  if (m < SUB - 16){
    u32 lo = (u32)f2bf(acc1[0]) | ((u32)f2bf(acc1[1]) << 16);
    u32 hi = (u32)f2bf(acc1[2]) | ((u32)f2bf(acc1[3]) << 16);
    u32* d = (u32*)(dst + (size_t)(16 + m)*T_DATA + t0 + i0);
    d[0] = lo; d[1] = hi;
  }
}

// ---- K2: grouped FIR convs via MFMA with DIRECT global B-loads + fused epilogue ----
template<bool G>
__device__ __forceinline__ bf16x8 loadw(const u16* __restrict__ row, long base){
  if (!G) return *(const bf16x8*)(row + base);
  union { bf16x8 v; u16 h[8]; } u;
#pragma unroll
  for (int e = 0; e < 8; e++){
    long idx = base + e;
    u.h[e] = (idx >= 0 && idx < T_DATA) ? row[idx] : (u16)0;
  }
  return u.v;
}

template<bool G>
__device__ __forceinline__ void conv_mfma(int wv, int lane, int c,
    const u16* __restrict__ xe, const u16* __restrict__ xi,
    const u16* __restrict__ zt, const u16* __restrict__ afrag, u16* rr)
{
  int m = lane & 15, kg = lane >> 4;
  int boffB = 16*m + 8*kg;
  int toff  = 16*m + 4*kg;
  long wbase = (long)c*TCH - 200 + boffB;

  if (wv < 2){
    int ch0 = wv*10;
#pragma unroll
    for (int g = 0; g < 2; g++){
      f32x4 acc[5];
#pragma unroll
      for (int q = 0; q < 5; q++){
        int ch = ch0 + g*5 + q;
        const u16* rowE = xe + (size_t)ch*T_DATA;
        const u16* rowI = xi + (size_t)ch*T_DATA;
        const u16* ae = afrag + (size_t)((0*SUB + ch)*KKN)*512 + lane*8;
        const u16* ai = afrag + (size_t)((1*SUB + ch)*KKN)*512 + lane*8;
        f32x4 a = {0.f,0.f,0.f,0.f};
#pragma unroll
        for (int kk = 0; kk < KKN; kk++){
          bf16x8 be = loadw<G>(rowE, wbase + 32*kk);
          bf16x8 bi = loadw<G>(rowI, wbase + 32*kk);
          a = __builtin_amdgcn_mfma_f32_16x16x32_bf16(*(const bf16x8*)(ae + kk*512), be, a, 0,0,0);
          a = __builtin_amdgcn_mfma_f32_16x16x32_bf16(*(const bf16x8*)(ai + kk*512), bi, a, 0,0,0);
        }
        acc[q] = a;
      }
#pragma unroll
      for (int q = 0; q < 5; q++){
        int ch = ch0 + g*5 + q;
        u32* d = (u32*)(rr + ch*TCH + toff);
        d[0] = (u32)f2bf(acc[q][0]) | ((u32)f2bf(acc[q][1]) << 16);
        d[1] = (u32)f2bf(acc[q][2]) | ((u32)f2bf(acc[q][3]) << 16);
      }
    }
  } else {
    int ch0 = (wv - 2)*10;
#pragma unroll
    for (int g = 0; g < 2; g++){
      f32x4 as[5], ah[5];
#pragma unroll
      for (int q = 0; q < 5; q++){
        int ch = ch0 + g*5 + q;
        const u16* rowZ = zt + (size_t)ch*T_DATA;
        const u16* a2 = afrag + (size_t)((2*SUB + ch)*KKN)*512 + lane*8;
        const u16* a3 = afrag + (size_t)((3*SUB + ch)*KKN)*512 + lane*8;
        f32x4 s = {0.f,0.f,0.f,0.f}, h = {0.f,0.f,0.f,0.f};
#pragma unroll
        for (int kk = 0; kk < KKN; kk++){
          bf16x8 bz = loadw<G>(rowZ, wbase + 32*kk);
          s = __builtin_amdgcn_mfma_f32_16x16x32_bf16(*(const bf16x8*)(a2 + kk*512), bz, s, 0,0,0);
          h = __builtin_amdgcn_mfma_f32_16x16x32_bf16(*(const bf16x8*)(a3 + kk*512), bz, h, 0,0,0);
        }
        as[q] = s; ah[q] = h;
      }
#pragma unroll
      for (int q = 0; q < 5; q++){
        int ch = ch0 + g*5 + q;
        u32* d1 = (u32*)(rr + (SUB + ch)*TCH + toff);
        d1[0] = (u32)f2bf(as[q][0]) | ((u32)f2bf(as[q][1]) << 16);
        d1[1] = (u32)f2bf(as[q][2]) | ((u32)f2bf(as[q][3]) << 16);
        u32* d2 = (u32*)(rr + (2*SUB + ch)*TCH + toff);
        d2[0] = (u32)f2bf(ah[q][0]) | ((u32)f2bf(ah[q][1]) << 16);
        d2[1] = (u32)f2bf(ah[q][2]) | ((u32)f2bf(ah[q][3]) << 16);
      }
    }
  }
}

__global__ __launch_bounds__(256, 4) void k_conv(
    const u16* __restrict__ xe, const u16* __restrict__ xi,
    const u16* __restrict__ zt, const u16* __restrict__ afrag,
    const float* __restrict__ Cden, const float* __restrict__ Theta,
    float* __restrict__ out)
{
  __shared__ __align__(16) u16 rr[3*SUB*TCH];    // 30,720 B (results; reused as P buf)
  __shared__ float lcden[SUB*SUB];
  __shared__ float lth[SUB];
  float* pbuf = (float*)rr;                      // [t*21 + sp], 21,504 B

  int tid = threadIdx.x;
  for (int i = tid; i < SUB*SUB; i += 256) lcden[i] = Cden[i];
  if (tid < SUB) lth[tid] = Theta[tid];

  // bijective XCD-aware chunk swizzle: consecutive chunks share an XCD L2
  int bid = blockIdx.x;
  int xcd = bid & 7, sb = bid >> 3;
  const int q8 = NCHUNKS_TOT >> 3, r8 = NCHUNKS_TOT & 7;   // 244, 2
  int c = (xcd < r8 ? xcd*(q8+1) : r8*(q8+1) + (xcd-r8)*q8) + sb;

  int wv = tid >> 6, lane = tid & 63;
  if (c > 0 && c < NCHUNKS_TOT-1)
    conv_mfma<false>(wv, lane, c, xe, xi, zt, afrag, rr);
  else
    conv_mfma<true >(wv, lane, c, xe, xi, zt, afrag, rr);
  __syncthreads();

  // ---- epilogue: P = sigmoid(syn + theta + hist + Cden @ spk) ----
  int t = tid;                   // 0..255
  float spkv[SUB];
#pragma unroll
  for (int s = 0; s < SUB; s++) spkv[s] = bf2f(rr[(SUB + s)*TCH + t]);
  float res[SUB];
#pragma unroll
  for (int sp = 0; sp < SUB; sp++){
    float msum = bf2f(rr[sp*TCH + t]) + lth[sp] + bf2f(rr[(2*SUB + sp)*TCH + t]);
#pragma unroll
    for (int s = 0; s < SUB; s++) msum += lcden[sp*SUB + s] * spkv[s];
    res[sp] = 1.0f/(1.0f + expf(-msum));
  }
  __syncthreads();               // all rr reads complete before overlay
#pragma unroll
  for (int sp = 0; sp < SUB; sp++) pbuf[t*21 + sp] = res[sp];
  __syncthreads();

  // ---- fully coalesced float4 copy-out ----
  int t0c = c*TCH;
  int tv = min(TCH, T_DATA - t0c);
  int np4 = tv*SUB/4;            // 20 % 4 == 0 -> no row crossing
  for (int i = tid; i < np4; i += 256){
    int p = i*4;
    int tt = p/20, sp = p - tt*20;
    float4 v;
    v.x = pbuf[tt*21 + sp];   v.y = pbuf[tt*21 + sp+1];
    v.z = pbuf[tt*21 + sp+2]; v.w = pbuf[tt*21 + sp+3];
    *(float4*)(out + (size_t)t0c*SUB + p) = v;
  }
}

extern "C" void kernel_launch(void* const* d_in, const int* in_sizes, int n_in,
                              void* d_out, int out_size, void* d_ws, size_t ws_size,
                              hipStream_t stream){
  const float* S_e  = (const float*)d_in[0];
  const float* S_i  = (const float*)d_in[1];
  const float* Z    = (const float*)d_in[2];
  const float* Cden = (const float*)d_in[3];
  const float* C_e  = (const float*)d_in[4];
  const float* C_i  = (const float*)d_in[5];
  const float* Tau  = (const float*)d_in[6];
  const float* Del  = (const float*)d_in[7];
  const float* Wsyn = (const float*)d_in[8];
  const float* Wspk = (const float*)d_in[9];
  const float* Whist= (const float*)d_in[10];
  const float* Theta= (const float*)d_in[11];
  float* out = (float*)d_out;

  // workspace layout (bf16 elements) — identical to passing round
  u16* xe    = (u16*)d_ws;
  u16* xi    = xe + (size_t)SUB*T_DATA;
  u16* zt    = xi + (size_t)SUB*T_DATA;
  u16* afrag = zt + (size_t)SUB*T_DATA;            // 4*20*7*512
  u16* bfrag = afrag + (size_t)4*SUB*KKN*512;      // 10240
  size_t need = ((size_t)3*SUB*T_DATA + (size_t)4*SUB*KKN*512 + 10240) * 2;
  if (ws_size < need) return;   // ~60.6 MB required

  k_filters<<<4*SUB, 64, 0, stream>>>(Tau, Del, Wsyn, Wspk, Whist, out);
  k_afrag<<<4*SUB*KKN, 64, 0, stream>>>(Tau, Del, Wsyn, Wspk, Whist, afrag);
  k_bfrag<<<4, 256, 0, stream>>>(C_e, C_i, bfrag);

  int gblk = (MT_TOT + 3)/4;
  k_gather<200,7><<<gblk, 256, 0, stream>>>(S_e, bfrag, xe);
  k_gather<50, 2><<<gblk, 256, 0, stream>>>(S_i, bfrag + 2*7*512, xi);
  k_gather<20, 1><<<gblk, 256, 0, stream>>>(Z,  bfrag + 2*7*512 + 2*2*512, zt);

  k_conv<<<NCHUNKS_TOT, 256, 0, stream>>>(xe, xi, zt, afrag, Cden, Theta, out);
}